// Round 5
// baseline (97419.202 us; speedup 1.0000x reference)
//
#include <hip/hip_runtime.h>
#include <hip/hip_bf16.h>
#include <math.h>

#define N_WORDS 8192
#define LMAX    16
#define WED     506
#define WHD     512
#define CED     6
#define CHD     6
#define CVOC    128
#define TAG     64
#define XDIM    512      // WED + CHD
#define G4      2048     // 4*WHD

// word-LSTM team config: 32 worker WGs co-located on ONE XCD, 16 units each
#define NLAUNCH 256      // launched WGs (1 per CU, all co-resident)
#define TEAM    32       // worker WGs (<= CUs per XCD)
#define UPB     16       // hidden units per worker WG
#define LPU     16       // lanes per unit
#define KC      32       // K elements per lane (strided by LPU)

__device__ __forceinline__ float fast_sigmoid(float x) { return 1.0f / (1.0f + __expf(-x)); }
__device__ __forceinline__ float fast_tanh(float x)    { return 2.0f / (1.0f + __expf(-2.0f * x)) - 1.0f; }

// ---------------- Kernel A: char-level LSTM, one thread per word ----------------
__global__ void __launch_bounds__(256) char_lstm_kernel(
    const int*   __restrict__ chars,     // [N, LMAX]
    const int*   __restrict__ lens,      // [N]
    const float* __restrict__ char_emb,  // [CVOC, CED]
    const float* __restrict__ cWih,      // [24, 6]
    const float* __restrict__ cWhh,      // [24, 6]
    const float* __restrict__ cb,        // [24]
    float*       __restrict__ h_char)    // [N, CHD]
{
    __shared__ float sWih[24][6], sWhh[24][6], sb[24], semb[CVOC][CED];
    int t = threadIdx.x;
    if (t < 144) { sWih[t / 6][t % 6] = cWih[t]; sWhh[t / 6][t % 6] = cWhh[t]; }
    if (t < 24) sb[t] = cb[t];
    for (int i = t; i < CVOC * CED; i += 256) semb[i / CED][i % CED] = char_emb[i];
    __syncthreads();

    int n = blockIdx.x * 256 + t;
    if (n >= N_WORDS) return;
    int len = lens[n];
    float h[CHD] = {0, 0, 0, 0, 0, 0};
    float c[CHD] = {0, 0, 0, 0, 0, 0};
    for (int l = 0; l < LMAX; ++l) {
        if (l >= len) break;  // once l >= len no further state updates occur
        int ch = chars[n * LMAX + l];
        float e[CED];
        #pragma unroll
        for (int k = 0; k < CED; ++k) e[k] = semb[ch][k];
        float pre[24];
        #pragma unroll
        for (int g = 0; g < 24; ++g) {
            float a = sb[g];
            #pragma unroll
            for (int k = 0; k < CED; ++k) a += e[k] * sWih[g][k];
            #pragma unroll
            for (int k = 0; k < CHD; ++k) a += h[k] * sWhh[g][k];
            pre[g] = a;
        }
        #pragma unroll
        for (int u = 0; u < CHD; ++u) {
            float ig = fast_sigmoid(pre[u]);
            float fg = fast_sigmoid(pre[6 + u]);
            float gg = fast_tanh(pre[12 + u]);
            float og = fast_sigmoid(pre[18 + u]);
            float cn = fg * c[u] + ig * gg;
            c[u] = cn;
            h[u] = og * fast_tanh(cn);
        }
    }
    for (int u = 0; u < CHD; ++u) h_char[n * CHD + u] = h[u];
}

// ---------------- Kernel B0: X = [word_emb gather | h_char] ----------------
__global__ void __launch_bounds__(256) build_x_kernel(
    const int*   __restrict__ words,
    const float* __restrict__ word_emb,  // [WV, WED]
    const float* __restrict__ h_char,    // [N, CHD]
    float*       __restrict__ X)         // [N, XDIM]
{
    long idx = (long)blockIdx.x * 256 + threadIdx.x;
    if (idx >= (long)N_WORDS * XDIM) return;
    int n = (int)(idx >> 9), k = (int)(idx & 511);
    float v;
    if (k < WED) v = word_emb[(long)words[n] * WED + k];
    else         v = h_char[n * CHD + (k - WED)];
    X[idx] = v;
}

// ---------------- Kernel B1: XP4 = X @ Wih^T + b, fp32 tiled GEMM ----------------
#define BM 64
#define BN 64
#define BK 16
__global__ void __launch_bounds__(256) xp_gemm_kernel(
    const float* __restrict__ X,    // [N, 512]
    const float* __restrict__ Wih,  // [2048, 512]
    const float* __restrict__ wb,   // [2048]
    float*       __restrict__ XP4)  // [N, 512, 4]
{
    __shared__ float As[BM][BK + 1];
    __shared__ float Bs[BN][BK + 1];
    int tid = threadIdx.x;
    int bm = (blockIdx.x % (N_WORDS / BM)) * BM;
    int bn = (blockIdx.x / (N_WORDS / BM)) * BN;
    int ty = tid / 16, tx = tid % 16;
    float acc[4][4] = {};
    for (int k0 = 0; k0 < XDIM; k0 += BK) {
        #pragma unroll
        for (int i = 0; i < 4; ++i) {
            int e = tid + i * 256;
            int r = e >> 4, cc = e & 15;
            As[r][cc] = X[(long)(bm + r) * XDIM + k0 + cc];
            Bs[r][cc] = Wih[(long)(bn + r) * XDIM + k0 + cc];
        }
        __syncthreads();
        #pragma unroll
        for (int kk = 0; kk < BK; ++kk) {
            float a[4], b[4];
            #pragma unroll
            for (int i = 0; i < 4; ++i) a[i] = As[ty * 4 + i][kk];
            #pragma unroll
            for (int j = 0; j < 4; ++j) b[j] = Bs[tx * 4 + j][kk];
            #pragma unroll
            for (int i = 0; i < 4; ++i)
                #pragma unroll
                for (int j = 0; j < 4; ++j) acc[i][j] += a[i] * b[j];
        }
        __syncthreads();
    }
    #pragma unroll
    for (int i = 0; i < 4; ++i) {
        int m = bm + ty * 4 + i;
        #pragma unroll
        for (int j = 0; j < 4; ++j) {
            int g = bn + tx * 4 + j;
            int unit = g & 511, gate = g >> 9;
            XP4[((long)m * WHD + unit) * 4 + gate] = acc[i][j] + wb[g];
        }
    }
}

// ---- sc0 (L1-bypass, L2-service) 8-byte load: intra-XCD coherent polling ----
__device__ __forceinline__ unsigned long long load_u64_sc0(const unsigned long long* p) {
    unsigned long long v;
    asm volatile("global_load_dwordx2 %0, %1, off sc0" : "=v"(v) : "v"(p) : "memory");
    return v;
}
__device__ __forceinline__ void wait_vm0() {
    asm volatile("s_waitcnt vmcnt(0)" ::: "memory");
}

// ---------------- Kernel C: sequential word LSTM, XCD-local team ----------------
// Phase A: 256 WGs (1/CU) ticket per-XCD counters; the WG drawing ticket TEAM-1
// elects its XCD via CAS. 32 WGs on the elected XCD become workers (16 units each);
// everyone else exits. All h-state communication then stays in THAT XCD's L2:
// polls via sc0 loads (~200cy) instead of agent/sc1 LLC loads (~600-900cy).
// Sentinel protocol unchanged: HS[t][u] written once as h+2.0; pre-zeroed; v>0.5==ready.
// Every 64th poll round falls back to an agent-scope load (guaranteed-fresh) so a
// wrong sc0-freshness assumption degrades to R4 latency instead of deadlocking.
__global__ void __launch_bounds__(256, 1) word_lstm_kernel(
    const float* __restrict__ Whh,  // [2048, 512]
    const float* __restrict__ XP4,  // [N, 512, 4] gate-interleaved
    float*       HS,                // [N, 512]; stores h+2.0; pre-zeroed
    int*         ctrl)              // [16] zeroed: [0..7] per-XCD tickets, [8] decided
{
    __shared__ int   s_rank;
    __shared__ float hbuf[WHD];

    const int tid = threadIdx.x;

    // ---- Phase A: team election ----
    if (tid == 0) {
        int xcd = __builtin_amdgcn_s_getreg((3 << 11) | (0 << 6) | 20) & 0xF;  // HW_REG_XCC_ID[3:0]
        int slot = atomicAdd(&ctrl[xcd], 1);              // device-scope
        if (slot == TEAM - 1) atomicCAS(&ctrl[8], 0, xcd + 1);
        int dec;
        while ((dec = __hip_atomic_load(&ctrl[8], __ATOMIC_RELAXED,
                                        __HIP_MEMORY_SCOPE_AGENT)) == 0) {
            __builtin_amdgcn_s_sleep(2);
        }
        s_rank = (xcd == dec - 1 && slot < TEAM) ? slot : -1;
    }
    __syncthreads();
    const int rank = s_rank;
    if (rank < 0) return;

    // ---- worker setup: rank owns units [rank*16, rank*16+16) ----
    const int ug = tid >> 4;         // 0..15 unit-in-block
    const int p  = tid & 15;         // lane within unit
    const int j  = rank * UPB + ug;  // hidden unit 0..511

    // weights for the strided K-set {p + 16*kk}
    float w[4][KC];
    #pragma unroll
    for (int r = 0; r < 4; ++r) {
        const float* src = Whh + (long)(r * 512 + j) * WHD + p;
        #pragma unroll
        for (int kk = 0; kk < KC; ++kk) w[r][kk] = src[kk * LPU];
    }

    float c = 0.0f;
    float h16[KC];
    #pragma unroll
    for (int kk = 0; kk < KC; ++kk) h16[kk] = 0.0f;

    for (int t = 0; t < N_WORDS; ++t) {
        const float4 xp = *(const float4*)(XP4 + ((long)t * WHD + j) * 4);

        if (t > 0) {
            if (tid < 64) {
                const unsigned long long* hrow =
                    (const unsigned long long*)(HS + (long)(t - 1) * WHD);
                float lo[4], hi[4];
                bool ready = false;
                int iter = 0;
                while (!ready) {
                    unsigned long long q[4];
                    if ((++iter & 63) != 0) {
                        // fast path: intra-XCD L2 reads
                        #pragma unroll
                        for (int i = 0; i < 4; ++i)
                            q[i] = load_u64_sc0(&hrow[i * 64 + tid]);
                        wait_vm0();
                    } else {
                        // progress guarantee: coherence-point reads
                        #pragma unroll
                        for (int i = 0; i < 4; ++i)
                            q[i] = __hip_atomic_load(&hrow[i * 64 + tid], __ATOMIC_RELAXED,
                                                     __HIP_MEMORY_SCOPE_AGENT);
                    }
                    ready = true;
                    #pragma unroll
                    for (int i = 0; i < 4; ++i) {
                        lo[i] = __uint_as_float((unsigned)(q[i] & 0xffffffffu));
                        hi[i] = __uint_as_float((unsigned)(q[i] >> 32));
                        ready = ready && (lo[i] > 0.5f) && (hi[i] > 0.5f);
                    }
                }
                #pragma unroll
                for (int i = 0; i < 4; ++i) {
                    hbuf[i * 128 + 2 * tid]     = lo[i] - 2.0f;
                    hbuf[i * 128 + 2 * tid + 1] = hi[i] - 2.0f;
                }
            }
            __syncthreads();
            #pragma unroll
            for (int kk = 0; kk < KC; ++kk) h16[kk] = hbuf[p + LPU * kk];
        }

        float di = 0, df = 0, dg = 0, dq = 0;
        #pragma unroll
        for (int kk = 0; kk < KC; ++kk) {
            di = fmaf(w[0][kk], h16[kk], di);
            df = fmaf(w[1][kk], h16[kk], df);
            dg = fmaf(w[2][kk], h16[kk], dg);
            dq = fmaf(w[3][kk], h16[kk], dq);
        }
        // reduce over the 16 lanes of this unit (xor masks < 16 stay in-group)
        #pragma unroll
        for (int m = 8; m >= 1; m >>= 1) {
            di += __shfl_xor(di, m);
            df += __shfl_xor(df, m);
            dg += __shfl_xor(dg, m);
            dq += __shfl_xor(dq, m);
        }
        float ig = fast_sigmoid(xp.x + di);
        float fg = fast_sigmoid(xp.y + df);
        float gg = fast_tanh(xp.z + dg);
        float og = fast_sigmoid(xp.w + dq);
        c = fg * c + ig * gg;
        float hn = og * fast_tanh(c);

        // plain (workgroup-scope) store: L1 is write-through, lands in the shared
        // XCD L2 where teammates' sc0 polls read it. No trailing barrier needed:
        // hbuf for t+1 is only overwritten after row t is fully stored, which
        // implies every wave consumed its step-t LDS reads.
        if (p == 0)
            __hip_atomic_store(&HS[(long)t * WHD + j], hn + 2.0f, __ATOMIC_RELAXED,
                               __HIP_MEMORY_SCOPE_WORKGROUP);
    }
}

// ---------------- Kernel D0: transpose out_W to [512][64] for coalesced reads ----------------
__global__ void __launch_bounds__(256) transpose_outw_kernel(
    const float* __restrict__ outW, float* __restrict__ outWT)
{
    int e = blockIdx.x * 256 + threadIdx.x;  // TAG*WHD
    if (e >= TAG * WHD) return;
    int g = e >> 9, k = e & 511;
    outWT[k * TAG + g] = outW[e];
}

// ---------------- Kernel D: logits + log_softmax, one wave per word ----------------
// HS holds h+2.0 -> subtract the offset inline.
__global__ void __launch_bounds__(64) logits_kernel(
    const float* __restrict__ HS,
    const float* __restrict__ outWT,   // [512][64]
    const float* __restrict__ outb,    // [64]
    float*       __restrict__ out)     // [N, 64]
{
    int n = blockIdx.x;
    int g = threadIdx.x;
    const float* hrow = HS + (long)n * WHD;
    float acc = outb[g];
    #pragma unroll 8
    for (int k = 0; k < WHD; ++k) acc += (hrow[k] - 2.0f) * outWT[k * TAG + g];
    float m = acc;
    #pragma unroll
    for (int s = 32; s >= 1; s >>= 1) m = fmaxf(m, __shfl_xor(m, s));
    float ex = __expf(acc - m);
    float ssum = ex;
    #pragma unroll
    for (int s = 32; s >= 1; s >>= 1) ssum += __shfl_xor(ssum, s);
    out[(long)n * TAG + g] = acc - m - logf(ssum);
}

extern "C" void kernel_launch(void* const* d_in, const int* in_sizes, int n_in,
                              void* d_out, int out_size, void* d_ws, size_t ws_size,
                              hipStream_t stream)
{
    const int*   words = (const int*)   d_in[0];
    const int*   chars = (const int*)   d_in[1];
    const int*   lens  = (const int*)   d_in[2];
    const float* wemb  = (const float*) d_in[3];
    const float* cemb  = (const float*) d_in[4];
    const float* cWih  = (const float*) d_in[5];
    const float* cWhh  = (const float*) d_in[6];
    const float* cb    = (const float*) d_in[7];
    const float* wWih  = (const float*) d_in[8];
    const float* wWhh  = (const float*) d_in[9];
    const float* wb    = (const float*) d_in[10];
    const float* outW  = (const float*) d_in[11];
    const float* outb  = (const float*) d_in[12];
    float* out = (float*)d_out;

    // workspace layout (bytes)
    char* ws = (char*)d_ws;
    size_t off = 0;
    float* h_char = (float*)(ws + off); off += (size_t)N_WORDS * CHD * 4;      // 196,608
    float* X      = (float*)(ws + off); off += (size_t)N_WORDS * XDIM * 4;     // 16.8 MB
    float* XP4    = (float*)(ws + off); off += (size_t)N_WORDS * G4 * 4;       // 67.1 MB
    float* HS     = (float*)(ws + off); off += (size_t)N_WORDS * WHD * 4;      // 16.8 MB
    float* outWT  = (float*)(ws + off); off += (size_t)WHD * TAG * 4;          // 128 KB
    int*   ctrl   = (int*)  (ws + off); off += 256;                            // election block

    // HS must be zero for the sentinel protocol; ctrl must be zero for the election.
    hipMemsetAsync(HS, 0, (size_t)N_WORDS * WHD * sizeof(float), stream);
    hipMemsetAsync(ctrl, 0, 256, stream);

    char_lstm_kernel<<<N_WORDS / 256, 256, 0, stream>>>(chars, lens, cemb, cWih, cWhh, cb, h_char);
    build_x_kernel<<<(N_WORDS * XDIM) / 256, 256, 0, stream>>>(words, wemb, h_char, X);
    xp_gemm_kernel<<<(N_WORDS / BM) * (G4 / BN), 256, 0, stream>>>(X, wWih, wb, XP4);
    transpose_outw_kernel<<<(TAG * WHD) / 256, 256, 0, stream>>>(outW, outWT);
    word_lstm_kernel<<<NLAUNCH, 256, 0, stream>>>(wWhh, XP4, HS, ctrl);
    logits_kernel<<<N_WORDS, 64, 0, stream>>>(HS, outWT, outb, out);
}

// Round 6
// 23004.485 us; speedup vs baseline: 4.2348x; 4.2348x over previous
//
#include <hip/hip_runtime.h>
#include <hip/hip_bf16.h>
#include <math.h>

#define N_WORDS 8192
#define LMAX    16
#define WED     506
#define WHD     512
#define CED     6
#define CHD     6
#define CVOC    128
#define TAG     64
#define XDIM    512      // WED + CHD
#define G4      2048     // 4*WHD
#define NWG     64       // workgroups for the word LSTM

__device__ __forceinline__ float fast_sigmoid(float x) { return 1.0f / (1.0f + __expf(-x)); }
__device__ __forceinline__ float fast_tanh(float x)    { return 2.0f / (1.0f + __expf(-2.0f * x)) - 1.0f; }

// ---------------- Kernel A: char-level LSTM, one thread per word ----------------
__global__ void __launch_bounds__(256) char_lstm_kernel(
    const int*   __restrict__ chars,     // [N, LMAX]
    const int*   __restrict__ lens,      // [N]
    const float* __restrict__ char_emb,  // [CVOC, CED]
    const float* __restrict__ cWih,      // [24, 6]
    const float* __restrict__ cWhh,      // [24, 6]
    const float* __restrict__ cb,        // [24]
    float*       __restrict__ h_char)    // [N, CHD]
{
    __shared__ float sWih[24][6], sWhh[24][6], sb[24], semb[CVOC][CED];
    int t = threadIdx.x;
    if (t < 144) { sWih[t / 6][t % 6] = cWih[t]; sWhh[t / 6][t % 6] = cWhh[t]; }
    if (t < 24) sb[t] = cb[t];
    for (int i = t; i < CVOC * CED; i += 256) semb[i / CED][i % CED] = char_emb[i];
    __syncthreads();

    int n = blockIdx.x * 256 + t;
    if (n >= N_WORDS) return;
    int len = lens[n];
    float h[CHD] = {0, 0, 0, 0, 0, 0};
    float c[CHD] = {0, 0, 0, 0, 0, 0};
    for (int l = 0; l < LMAX; ++l) {
        if (l >= len) break;  // once l >= len no further state updates occur
        int ch = chars[n * LMAX + l];
        float e[CED];
        #pragma unroll
        for (int k = 0; k < CED; ++k) e[k] = semb[ch][k];
        float pre[24];
        #pragma unroll
        for (int g = 0; g < 24; ++g) {
            float a = sb[g];
            #pragma unroll
            for (int k = 0; k < CED; ++k) a += e[k] * sWih[g][k];
            #pragma unroll
            for (int k = 0; k < CHD; ++k) a += h[k] * sWhh[g][k];
            pre[g] = a;
        }
        #pragma unroll
        for (int u = 0; u < CHD; ++u) {
            float ig = fast_sigmoid(pre[u]);
            float fg = fast_sigmoid(pre[6 + u]);
            float gg = fast_tanh(pre[12 + u]);
            float og = fast_sigmoid(pre[18 + u]);
            float cn = fg * c[u] + ig * gg;
            c[u] = cn;
            h[u] = og * fast_tanh(cn);
        }
    }
    for (int u = 0; u < CHD; ++u) h_char[n * CHD + u] = h[u];
}

// ---------------- Kernel B0: X = [word_emb gather | h_char] ----------------
__global__ void __launch_bounds__(256) build_x_kernel(
    const int*   __restrict__ words,
    const float* __restrict__ word_emb,  // [WV, WED]
    const float* __restrict__ h_char,    // [N, CHD]
    float*       __restrict__ X)         // [N, XDIM]
{
    long idx = (long)blockIdx.x * 256 + threadIdx.x;
    if (idx >= (long)N_WORDS * XDIM) return;
    int n = (int)(idx >> 9), k = (int)(idx & 511);
    float v;
    if (k < WED) v = word_emb[(long)words[n] * WED + k];
    else         v = h_char[n * CHD + (k - WED)];
    X[idx] = v;
}

// ---------------- Kernel B1: XP4 = X @ Wih^T + b, fp32 tiled GEMM ----------------
#define BM 64
#define BN 64
#define BK 16
__global__ void __launch_bounds__(256) xp_gemm_kernel(
    const float* __restrict__ X,    // [N, 512]
    const float* __restrict__ Wih,  // [2048, 512]
    const float* __restrict__ wb,   // [2048]
    float*       __restrict__ XP4)  // [N, 512, 4]
{
    __shared__ float As[BM][BK + 1];
    __shared__ float Bs[BN][BK + 1];
    int tid = threadIdx.x;
    int bm = (blockIdx.x % (N_WORDS / BM)) * BM;
    int bn = (blockIdx.x / (N_WORDS / BM)) * BN;
    int ty = tid / 16, tx = tid % 16;
    float acc[4][4] = {};
    for (int k0 = 0; k0 < XDIM; k0 += BK) {
        #pragma unroll
        for (int i = 0; i < 4; ++i) {
            int e = tid + i * 256;
            int r = e >> 4, cc = e & 15;
            As[r][cc] = X[(long)(bm + r) * XDIM + k0 + cc];
            Bs[r][cc] = Wih[(long)(bn + r) * XDIM + k0 + cc];
        }
        __syncthreads();
        #pragma unroll
        for (int kk = 0; kk < BK; ++kk) {
            float a[4], b[4];
            #pragma unroll
            for (int i = 0; i < 4; ++i) a[i] = As[ty * 4 + i][kk];
            #pragma unroll
            for (int j = 0; j < 4; ++j) b[j] = Bs[tx * 4 + j][kk];
            #pragma unroll
            for (int i = 0; i < 4; ++i)
                #pragma unroll
                for (int j = 0; j < 4; ++j) acc[i][j] += a[i] * b[j];
        }
        __syncthreads();
    }
    #pragma unroll
    for (int i = 0; i < 4; ++i) {
        int m = bm + ty * 4 + i;
        #pragma unroll
        for (int j = 0; j < 4; ++j) {
            int g = bn + tx * 4 + j;
            int unit = g & 511, gate = g >> 9;
            XP4[((long)m * WHD + unit) * 4 + gate] = acc[i][j] + wb[g];
        }
    }
}

// ---------------- Kernel C: sequential word LSTM (R4 protocol + LDS-resident weights) ----------------
// WG wg owns hidden units j in [wg*8, wg*8+8). 32 lanes per unit; lane p owns the
// strided K-set {p + 32*kk : kk in [0,16)}. Weights are staged ONCE into LDS as
// packed bf16 pairs (32 KB) -> per-step weight access is ds_read_b64, never global
// (R4/R5 showed the compiler rematerializes global weight loads inside the t-loop:
// VGPR_Count 56/92 < live-weight requirement; concentrated on one XCD this thrashed
// L2 -> the R5 collapse. LDS staging makes weight traffic deterministic.)
// Exchange protocol (unchanged from R4): HS[t][u] written once as h+2.0 (in [1,3]);
// HS pre-zeroed; ready <=> v>0.5. Only wave 0 polls, with coalesced u64 agent-scope
// loads, then relays via LDS. Per-u64 early-exit + s_sleep backoff limit LLC pressure.
__global__ void __launch_bounds__(256, 1) word_lstm_kernel(
    const float* __restrict__ Whh,  // [2048, 512]
    const float* __restrict__ XP4,  // [N, 512, 4] gate-interleaved
    float*       HS)                // [N, 512]; stores h+2.0; pre-zeroed
{
    // wlds[(v*16+s)*64 + l]: for wave v, lane l, slot s: 4 bf16 weights
    // (gate r=s>>2, kk = (s&3)*4 .. +3). 4*16*64*8 B = 32 KB.
    __shared__ uint2 wlds[4 * 16 * 64];
    __shared__ float hbuf[WHD];     // h[t-1] (offset removed)

    const int tid = threadIdx.x;
    const int wg  = blockIdx.x;      // 0..63
    const int v   = tid >> 6;        // wave 0..3
    const int l   = tid & 63;        // lane
    const int ug  = tid >> 5;        // 0..7 unit-in-block
    const int p   = tid & 31;        // K-part within unit
    const int j   = wg * 8 + ug;     // hidden unit 0..511

    // ---- one-time LDS weight staging ----
    #pragma unroll
    for (int s = 0; s < 16; ++s) {
        int r  = s >> 2;
        int kb = (s & 3) * 4;
        const float* src = Whh + (long)(r * 512 + j) * WHD + p;
        unsigned short b[4];
        #pragma unroll
        for (int i = 0; i < 4; ++i) {
            __hip_bfloat16 hb = __float2bfloat16(src[(kb + i) * 32]);
            b[i] = *(unsigned short*)&hb;
        }
        wlds[(v * 16 + s) * 64 + l] =
            make_uint2((unsigned)b[0] | ((unsigned)b[1] << 16),
                       (unsigned)b[2] | ((unsigned)b[3] << 16));
    }
    __syncthreads();

    float c = 0.0f;
    float h16[16];
    #pragma unroll
    for (int kk = 0; kk < 16; ++kk) h16[kk] = 0.0f;

    for (int t = 0; t < N_WORDS; ++t) {
        // xp load depends only on t -> issue before the poll so its latency hides
        const float4 xp = *(const float4*)(XP4 + ((long)t * WHD + j) * 4);

        if (t > 0) {
            if (tid < 64) {
                const unsigned long long* hrow =
                    (const unsigned long long*)(HS + (long)(t - 1) * WHD);
                float lo[4], hi[4];
                bool done0 = false, done1 = false, done2 = false, done3 = false;
                int fails = 0;
                for (;;) {
                    unsigned long long q;
                    if (!done0) {
                        q = __hip_atomic_load(&hrow[0 * 64 + tid], __ATOMIC_RELAXED,
                                              __HIP_MEMORY_SCOPE_AGENT);
                        lo[0] = __uint_as_float((unsigned)(q & 0xffffffffu));
                        hi[0] = __uint_as_float((unsigned)(q >> 32));
                        done0 = (lo[0] > 0.5f) && (hi[0] > 0.5f);
                    }
                    if (!done1) {
                        q = __hip_atomic_load(&hrow[1 * 64 + tid], __ATOMIC_RELAXED,
                                              __HIP_MEMORY_SCOPE_AGENT);
                        lo[1] = __uint_as_float((unsigned)(q & 0xffffffffu));
                        hi[1] = __uint_as_float((unsigned)(q >> 32));
                        done1 = (lo[1] > 0.5f) && (hi[1] > 0.5f);
                    }
                    if (!done2) {
                        q = __hip_atomic_load(&hrow[2 * 64 + tid], __ATOMIC_RELAXED,
                                              __HIP_MEMORY_SCOPE_AGENT);
                        lo[2] = __uint_as_float((unsigned)(q & 0xffffffffu));
                        hi[2] = __uint_as_float((unsigned)(q >> 32));
                        done2 = (lo[2] > 0.5f) && (hi[2] > 0.5f);
                    }
                    if (!done3) {
                        q = __hip_atomic_load(&hrow[3 * 64 + tid], __ATOMIC_RELAXED,
                                              __HIP_MEMORY_SCOPE_AGENT);
                        lo[3] = __uint_as_float((unsigned)(q & 0xffffffffu));
                        hi[3] = __uint_as_float((unsigned)(q >> 32));
                        done3 = (lo[3] > 0.5f) && (hi[3] > 0.5f);
                    }
                    if (done0 && done1 && done2 && done3) break;
                    if (++fails >= 3) __builtin_amdgcn_s_sleep(2);
                }
                #pragma unroll
                for (int i = 0; i < 4; ++i) {
                    hbuf[i * 128 + 2 * tid]     = lo[i] - 2.0f;
                    hbuf[i * 128 + 2 * tid + 1] = hi[i] - 2.0f;
                }
            }
            __syncthreads();
            #pragma unroll
            for (int kk = 0; kk < 16; ++kk) h16[kk] = hbuf[p + 32 * kk];
        }

        float acc[4] = {0.0f, 0.0f, 0.0f, 0.0f};
        #pragma unroll
        for (int s = 0; s < 16; ++s) {
            uint2 qw = wlds[(v * 16 + s) * 64 + l];
            int r  = s >> 2;
            int kb = (s & 3) * 4;
            float w0 = __uint_as_float(qw.x << 16);
            float w1 = __uint_as_float(qw.x & 0xffff0000u);
            float w2 = __uint_as_float(qw.y << 16);
            float w3 = __uint_as_float(qw.y & 0xffff0000u);
            acc[r] = fmaf(w0, h16[kb + 0], acc[r]);
            acc[r] = fmaf(w1, h16[kb + 1], acc[r]);
            acc[r] = fmaf(w2, h16[kb + 2], acc[r]);
            acc[r] = fmaf(w3, h16[kb + 3], acc[r]);
        }
        // reduce over the 32 lanes of this unit (xor masks < 32 stay in each half-wave)
        #pragma unroll
        for (int m = 16; m >= 1; m >>= 1) {
            acc[0] += __shfl_xor(acc[0], m);
            acc[1] += __shfl_xor(acc[1], m);
            acc[2] += __shfl_xor(acc[2], m);
            acc[3] += __shfl_xor(acc[3], m);
        }
        float ig = fast_sigmoid(xp.x + acc[0]);
        float fg = fast_sigmoid(xp.y + acc[1]);
        float gg = fast_tanh(xp.z + acc[2]);
        float og = fast_sigmoid(xp.w + acc[3]);
        c = fg * c + ig * gg;
        float hn = og * fast_tanh(c);

        if (p == 0)
            __hip_atomic_store(&HS[(long)t * WHD + j], hn + 2.0f, __ATOMIC_RELAXED,
                               __HIP_MEMORY_SCOPE_AGENT);
        // No trailing barrier needed: wave 0 only overwrites hbuf for step t+1 after
        // ALL 512 h[t] values are globally visible, which implies every wave
        // (including ours) already consumed its step-t LDS reads.
    }
}

// ---------------- Kernel D0: transpose out_W to [512][64] for coalesced reads ----------------
__global__ void __launch_bounds__(256) transpose_outw_kernel(
    const float* __restrict__ outW, float* __restrict__ outWT)
{
    int e = blockIdx.x * 256 + threadIdx.x;  // TAG*WHD
    if (e >= TAG * WHD) return;
    int g = e >> 9, k = e & 511;
    outWT[k * TAG + g] = outW[e];
}

// ---------------- Kernel D: logits + log_softmax, one wave per word ----------------
// HS holds h+2.0 -> subtract the offset inline.
__global__ void __launch_bounds__(64) logits_kernel(
    const float* __restrict__ HS,
    const float* __restrict__ outWT,   // [512][64]
    const float* __restrict__ outb,    // [64]
    float*       __restrict__ out)     // [N, 64]
{
    int n = blockIdx.x;
    int g = threadIdx.x;
    const float* hrow = HS + (long)n * WHD;
    float acc = outb[g];
    #pragma unroll 8
    for (int k = 0; k < WHD; ++k) acc += (hrow[k] - 2.0f) * outWT[k * TAG + g];
    float m = acc;
    #pragma unroll
    for (int s = 32; s >= 1; s >>= 1) m = fmaxf(m, __shfl_xor(m, s));
    float ex = __expf(acc - m);
    float ssum = ex;
    #pragma unroll
    for (int s = 32; s >= 1; s >>= 1) ssum += __shfl_xor(ssum, s);
    out[(long)n * TAG + g] = acc - m - logf(ssum);
}

extern "C" void kernel_launch(void* const* d_in, const int* in_sizes, int n_in,
                              void* d_out, int out_size, void* d_ws, size_t ws_size,
                              hipStream_t stream)
{
    const int*   words = (const int*)   d_in[0];
    const int*   chars = (const int*)   d_in[1];
    const int*   lens  = (const int*)   d_in[2];
    const float* wemb  = (const float*) d_in[3];
    const float* cemb  = (const float*) d_in[4];
    const float* cWih  = (const float*) d_in[5];
    const float* cWhh  = (const float*) d_in[6];
    const float* cb    = (const float*) d_in[7];
    const float* wWih  = (const float*) d_in[8];
    const float* wWhh  = (const float*) d_in[9];
    const float* wb    = (const float*) d_in[10];
    const float* outW  = (const float*) d_in[11];
    const float* outb  = (const float*) d_in[12];
    float* out = (float*)d_out;

    // workspace layout (bytes)
    char* ws = (char*)d_ws;
    size_t off = 0;
    float* h_char = (float*)(ws + off); off += (size_t)N_WORDS * CHD * 4;      // 196,608
    float* X      = (float*)(ws + off); off += (size_t)N_WORDS * XDIM * 4;     // 16.8 MB
    float* XP4    = (float*)(ws + off); off += (size_t)N_WORDS * G4 * 4;       // 67.1 MB
    float* HS     = (float*)(ws + off); off += (size_t)N_WORDS * WHD * 4;      // 16.8 MB
    float* outWT  = (float*)(ws + off); off += (size_t)WHD * TAG * 4;          // 128 KB

    // HS must be zero so the sentinel protocol (stored h+2 > 0.5) is well-defined.
    hipMemsetAsync(HS, 0, (size_t)N_WORDS * WHD * sizeof(float), stream);

    char_lstm_kernel<<<N_WORDS / 256, 256, 0, stream>>>(chars, lens, cemb, cWih, cWhh, cb, h_char);
    build_x_kernel<<<(N_WORDS * XDIM) / 256, 256, 0, stream>>>(words, wemb, h_char, X);
    xp_gemm_kernel<<<(N_WORDS / BM) * (G4 / BN), 256, 0, stream>>>(X, wWih, wb, XP4);
    transpose_outw_kernel<<<(TAG * WHD) / 256, 256, 0, stream>>>(outW, outWT);
    word_lstm_kernel<<<NWG, 256, 0, stream>>>(wWhh, XP4, HS);
    logits_kernel<<<N_WORDS, 64, 0, stream>>>(HS, outWT, outb, out);
}